// Round 1
// baseline (643.182 us; speedup 1.0000x reference)
//
#include <hip/hip_runtime.h>

typedef unsigned short u16;
typedef unsigned int   u32;
typedef __attribute__((ext_vector_type(8))) short short8;   // 8 x bf16 (guide §3)
typedef __attribute__((ext_vector_type(4))) float f32x4;

__device__ __forceinline__ float b2f(u16 u) {
  union { float f; u32 i; } v; v.i = ((u32)u) << 16; return v.f;
}
__device__ __forceinline__ u16 f2b(float f) {
  union { float f; u32 i; } v; v.f = f;
  u32 r = v.i + 0x7fffu + ((v.i >> 16) & 1u);   // RNE
  return (u16)(r >> 16);
}

__device__ __forceinline__ void gload_lds16(const void* g, void* l) {
  __builtin_amdgcn_global_load_lds(
      (const __attribute__((address_space(1))) void*)g,
      (__attribute__((address_space(3))) void*)l, 16, 0, 0);
}

// ---------------- f32 -> bf16 convert ----------------
__global__ __launch_bounds__(256) void cvt_bf16(const float* __restrict__ in,
                                                u16* __restrict__ out, int n4) {
  for (long i = (long)blockIdx.x * 256 + threadIdx.x; i < n4; i += (long)gridDim.x * 256) {
    const float4 v = ((const float4*)in)[i];
    ushort4 o;
    o.x = f2b(v.x); o.y = f2b(v.y); o.z = f2b(v.z); o.w = f2b(v.w);
    ((ushort4*)out)[i] = o;
  }
}

// ---------------- GEMM: C(MxN) = A(MxK) * B(NxK)^T, bf16 in, OutT out -------
// m97 structure: 128x128 tile, BK=32, 4 waves (2x2), 16x16x32 MFMA,
// global_load_lds width-16 staging.
template <typename OutT>
__global__ __launch_bounds__(256) void gemm_bt(const u16* __restrict__ A,
                                               const u16* __restrict__ B,
                                               OutT* __restrict__ C,
                                               int M, int N, int K) {
  __shared__ u16 As[128 * 32];
  __shared__ u16 Bs[128 * 32];
  const int tid = threadIdx.x;
  const int wid = tid >> 6, lane = tid & 63;
  const int fr = lane & 15, fq = lane >> 4;
  const int wr = wid >> 1, wc = wid & 1;
  const long row0 = (long)blockIdx.y * 128;
  const long col0 = (long)blockIdx.x * 128;
  const int scol = (lane & 3) * 8;          // 16B chunk within a 32-elem row
  const int srow = lane >> 2;               // row within 16-row chunk

  f32x4 acc[4][4];
#pragma unroll
  for (int m = 0; m < 4; ++m)
#pragma unroll
    for (int n = 0; n < 4; ++n) acc[m][n] = f32x4{0.f, 0.f, 0.f, 0.f};

  for (int k0 = 0; k0 < K; k0 += 32) {
#pragma unroll
    for (int i = 0; i < 2; ++i) {
      const int c = wid * 2 + i;            // 8 chunks of 1024B each (16 rows)
      const int r = c * 16 + srow;
      gload_lds16(A + (row0 + r) * K + k0 + scol, (char*)As + c * 1024);
      gload_lds16(B + (col0 + r) * K + k0 + scol, (char*)Bs + c * 1024);
    }
    __syncthreads();
    short8 a[4], b[4];
#pragma unroll
    for (int m = 0; m < 4; ++m)
      a[m] = *(const short8*)(As + (wr * 64 + m * 16 + fr) * 32 + fq * 8);
#pragma unroll
    for (int n = 0; n < 4; ++n)
      b[n] = *(const short8*)(Bs + (wc * 64 + n * 16 + fr) * 32 + fq * 8);
#pragma unroll
    for (int m = 0; m < 4; ++m)
#pragma unroll
      for (int n = 0; n < 4; ++n)
        acc[m][n] = __builtin_amdgcn_mfma_f32_16x16x32_bf16(a[m], b[n], acc[m][n], 0, 0, 0);
    __syncthreads();
  }

#pragma unroll
  for (int m = 0; m < 4; ++m)
#pragma unroll
    for (int n = 0; n < 4; ++n)
#pragma unroll
      for (int j = 0; j < 4; ++j) {
        const long r = row0 + wr * 64 + m * 16 + fq * 4 + j;
        const long c = col0 + wc * 64 + n * 16 + fr;
        if constexpr (sizeof(OutT) == 2) C[r * N + c] = f2b(acc[m][n][j]);
        else                             C[r * N + c] = acc[m][n][j];
      }
}

// ---------------- RoPE in-place on q,k (cols 0..8191 of qkv) ----------------
// Folds attention scale 1/sqrt(128) into q.
__global__ __launch_bounds__(256) void rope_qk(u16* __restrict__ qkv,
                                               const float* __restrict__ cosb,
                                               const float* __restrict__ sinb) {
  const int s = blockIdx.x;
  __shared__ u16 row[8192];
  const uint4* src = (const uint4*)(qkv + (long)s * 12288);
  uint4* dst = (uint4*)row;
  for (int i = threadIdx.x; i < 1024; i += 256) dst[i] = src[i];
  __syncthreads();
  const float scale = 0.08838834764831845f;  // 1/sqrt(128)
  for (int i = threadIdx.x; i < 8192; i += 256) {
    const int d = i & 127;
    const int base = i & ~127;
    const float x  = b2f(row[i]);
    const float x2 = b2f(row[base + ((d + 64) & 127)]);
    const float c  = cosb[s * 128 + d];
    const float sn = sinb[s * 128 + d];
    float v = x * c + ((d < 64) ? -x2 : x2) * sn;
    if (i < 4096) v *= scale;                // q only
    qkv[(long)s * 12288 + i] = f2b(v);
  }
}

// ---------------- transpose V: qkv[:,8192+f] (S x 4096) -> vt (4096 x S) ----
__global__ __launch_bounds__(256) void transpose_v(const u16* __restrict__ qkv,
                                                   u16* __restrict__ vt) {
  __shared__ u16 tile[64][72];               // +8 pad: conflict-free gather
  const int f0 = blockIdx.x * 64;
  const int s0 = blockIdx.y * 64;
  const int tid = threadIdx.x;
  const int rr = tid >> 3;                   // 0..31
  const int cc = (tid & 7) * 8;              // 0,8,..,56
#pragma unroll
  for (int p = 0; p < 2; ++p) {
    const int sr = p * 32 + rr;
    *(uint4*)&tile[sr][cc] =
        *(const uint4*)(qkv + (long)(s0 + sr) * 12288 + 8192 + f0 + cc);
  }
  __syncthreads();
#pragma unroll
  for (int p = 0; p < 2; ++p) {
    const int fr = p * 32 + rr;
    u16 tmp[8];
#pragma unroll
    for (int j = 0; j < 8; ++j) tmp[j] = tile[cc + j][fr];
    *(uint4*)(vt + (long)(f0 + fr) * 2048 + s0 + cc) = *(uint4*)tmp;
  }
}

// ---------------- causal flash attention ------------------------------------
// grid (S/64, H), 256 thr = 4 waves; wave owns 16 q-rows; KV tiles of 64.
// K staged [64][128] with XOR-swizzled source (rule 21), V staged from
// pre-transposed vt as [128][64] likewise swizzled. P via padded per-wave LDS.
__global__ __launch_bounds__(256) void attn_fwd(const u16* __restrict__ Qb,
                                                const u16* __restrict__ Kb,
                                                const u16* __restrict__ Vt,
                                                u16* __restrict__ Ob) {
  const int h  = blockIdx.y;
  const int q0 = blockIdx.x * 64;
  const int tid = threadIdx.x;
  const int wid = tid >> 6, lane = tid & 63;
  const int fr = lane & 15, fq = lane >> 4;

  __shared__ u16 Ks[64 * 128];    // 16 KB, physical chunk p holds logical p^(r&7)
  __shared__ u16 Vts[128 * 64];   // 16 KB, same swizzle on 8 chunks/row
  __shared__ u16 Ps[4][16 * 72];  // per-wave P tile, padded pitch

  short8 qf[4];
  {
    const long qrow = q0 + wid * 16 + fr;
#pragma unroll
    for (int kk = 0; kk < 4; ++kk)
      qf[kk] = *(const short8*)(Qb + qrow * 12288 + h * 128 + kk * 32 + fq * 8);
  }

  f32x4 Oacc[8];
#pragma unroll
  for (int f = 0; f < 8; ++f) Oacc[f] = f32x4{0.f, 0.f, 0.f, 0.f};
  float mrun[4], lrun[4];
#pragma unroll
  for (int j = 0; j < 4; ++j) { mrun[j] = -1e30f; lrun[j] = 0.f; }

  const int nt = blockIdx.x + 1;
  for (int t = 0; t < nt; ++t) {
    const int kv0 = t * 64;
#pragma unroll
    for (int i = 0; i < 4; ++i) {
      const int c = wid * 4 + i;
      {  // K tile: 4 rows (256B) per 1024B chunk
        const int r = c * 4 + (lane >> 4);
        const int p = lane & 15;
        const int jsrc = p ^ (r & 7);
        gload_lds16(Kb + (long)(kv0 + r) * 12288 + h * 128 + jsrc * 8,
                    (char*)Ks + c * 1024);
      }
      {  // Vt tile: 8 rows (128B) per chunk
        const int d = c * 8 + (lane >> 3);
        const int p = lane & 7;
        const int jsrc = p ^ (d & 7);
        gload_lds16(Vt + (long)(h * 128 + d) * 2048 + kv0 + jsrc * 8,
                    (char*)Vts + c * 1024);
      }
    }
    __syncthreads();

    // QK^T: S[16 q][64 kv] per wave
    f32x4 S[4];
#pragma unroll
    for (int n = 0; n < 4; ++n) S[n] = f32x4{0.f, 0.f, 0.f, 0.f};
#pragma unroll
    for (int kk = 0; kk < 4; ++kk) {
#pragma unroll
      for (int n = 0; n < 4; ++n) {
        const int r = n * 16 + fr;                       // kv row
        const int p = (kk * 4 + fq) ^ (r & 7);           // swizzled 16B chunk
        short8 kf = *(const short8*)((const char*)Ks + r * 256 + p * 16);
        S[n] = __builtin_amdgcn_mfma_f32_16x16x32_bf16(qf[kk], kf, S[n], 0, 0, 0);
      }
    }

    // mask + online softmax (scale already folded into q)
    float P[4][4];
    float tm[4] = {-1e30f, -1e30f, -1e30f, -1e30f};
#pragma unroll
    for (int n = 0; n < 4; ++n) {
      const int kv = kv0 + n * 16 + fr;
#pragma unroll
      for (int j = 0; j < 4; ++j) {
        const int qi = q0 + wid * 16 + fq * 4 + j;
        const float s = (kv <= qi) ? S[n][j] : -1e30f;
        P[n][j] = s;
        tm[j] = fmaxf(tm[j], s);
      }
    }
#pragma unroll
    for (int j = 0; j < 4; ++j)
#pragma unroll
      for (int msk = 1; msk < 16; msk <<= 1)
        tm[j] = fmaxf(tm[j], __shfl_xor(tm[j], msk));

    float al[4], rs[4];
#pragma unroll
    for (int j = 0; j < 4; ++j) {
      const float mn = fmaxf(mrun[j], tm[j]);
      al[j] = __expf(mrun[j] - mn);
      mrun[j] = mn;
      rs[j] = 0.f;
    }
#pragma unroll
    for (int n = 0; n < 4; ++n)
#pragma unroll
      for (int j = 0; j < 4; ++j) {
        const float p = __expf(P[n][j] - mrun[j]);
        P[n][j] = p;
        rs[j] += p;
      }
#pragma unroll
    for (int j = 0; j < 4; ++j) {
#pragma unroll
      for (int msk = 1; msk < 16; msk <<= 1) rs[j] += __shfl_xor(rs[j], msk);
      lrun[j] = lrun[j] * al[j] + rs[j];
    }
#pragma unroll
    for (int f = 0; f < 8; ++f) {
      f32x4 o = Oacc[f];
#pragma unroll
      for (int j = 0; j < 4; ++j) o[j] *= al[j];
      Oacc[f] = o;
    }

    // P (C-layout) -> padded LDS -> A-layout
#pragma unroll
    for (int n = 0; n < 4; ++n)
#pragma unroll
      for (int j = 0; j < 4; ++j)
        Ps[wid][(fq * 4 + j) * 72 + n * 16 + fr] = f2b(P[n][j]);

    // PV: O[16 q][128 d] += P * V
#pragma unroll
    for (int kb = 0; kb < 2; ++kb) {
      short8 pa = *(const short8*)(Ps[wid] + fr * 72 + kb * 32 + fq * 8);
#pragma unroll
      for (int f = 0; f < 8; ++f) {
        const int d = f * 16 + fr;
        const int p = (kb * 4 + fq) ^ (d & 7);
        short8 vf = *(const short8*)((const char*)Vts + d * 128 + p * 16);
        Oacc[f] = __builtin_amdgcn_mfma_f32_16x16x32_bf16(pa, vf, Oacc[f], 0, 0, 0);
      }
    }
    __syncthreads();
  }

#pragma unroll
  for (int j = 0; j < 4; ++j) {
    const float inv = 1.f / lrun[j];
    const long r = q0 + wid * 16 + fq * 4 + j;
#pragma unroll
    for (int f = 0; f < 8; ++f)
      Ob[r * 4096 + h * 128 + f * 16 + fr] = f2b(Oacc[f][j] * inv);
  }
}

// ---------------- launch ----------------------------------------------------
extern "C" void kernel_launch(void* const* d_in, const int* in_sizes, int n_in,
                              void* d_out, int out_size, void* d_ws, size_t ws_size,
                              hipStream_t stream) {
  const float* hs   = (const float*)d_in[0];   // (2048, 4096)
  const float* cosb = (const float*)d_in[1];   // (2048, 128)
  const float* sinb = (const float*)d_in[2];   // (2048, 128)
  const float* wp   = (const float*)d_in[3];   // (12288, 4096)
  const float* wo   = (const float*)d_in[4];   // (4096, 4096)
  float* out = (float*)d_out;                  // (2048, 4096)
  char* ws = (char*)d_ws;

  // workspace layout (bytes); wo_bf reuses w_pack slot after GEMM1,
  // attn reuses h_bf slot after GEMM1. Total: 184,549,376 B.
  u16* wp_bf = (u16*)(ws);                       // 100,663,296 B
  u16* wo_bf = (u16*)(ws);                       //  33,554,432 B (after GEMM1)
  u16* h_bf  = (u16*)(ws + 100663296);           //  16,777,216 B
  u16* attn  = (u16*)(ws + 100663296);           //  16,777,216 B (after GEMM1)
  u16* qkv   = (u16*)(ws + 117440512);           //  50,331,648 B
  u16* vt    = (u16*)(ws + 167772160);           //  16,777,216 B

  cvt_bf16<<<2048, 256, 0, stream>>>(hs, h_bf, 8388608 / 4);
  cvt_bf16<<<4096, 256, 0, stream>>>(wp, wp_bf, 50331648 / 4);
  gemm_bt<u16><<<dim3(96, 16), 256, 0, stream>>>(h_bf, wp_bf, qkv, 2048, 12288, 4096);
  rope_qk<<<2048, 256, 0, stream>>>(qkv, cosb, sinb);
  transpose_v<<<dim3(64, 32), 256, 0, stream>>>(qkv, vt);
  cvt_bf16<<<2048, 256, 0, stream>>>(wo, wo_bf, 16777216 / 4);
  attn_fwd<<<dim3(32, 32), 256, 0, stream>>>(qkv, qkv + 4096, vt, attn);
  gemm_bt<float><<<dim3(32, 16), 256, 0, stream>>>(attn, wo_bf, out, 2048, 4096, 4096);
}

// Round 2
// 553.489 us; speedup vs baseline: 1.1621x; 1.1621x over previous
//
#include <hip/hip_runtime.h>

typedef unsigned short u16;
typedef unsigned int   u32;
typedef __attribute__((ext_vector_type(8))) short short8;   // 8 x bf16
typedef __attribute__((ext_vector_type(4))) float f32x4;

__device__ __forceinline__ float b2f(u16 u) {
  union { float f; u32 i; } v; v.i = ((u32)u) << 16; return v.f;
}
__device__ __forceinline__ u16 f2b(float f) {
  union { float f; u32 i; } v; v.f = f;
  u32 r = v.i + 0x7fffu + ((v.i >> 16) & 1u);   // RNE
  return (u16)(r >> 16);
}

__device__ __forceinline__ void gload_lds16(const void* g, void* l) {
  __builtin_amdgcn_global_load_lds(
      (const __attribute__((address_space(1))) void*)g,
      (__attribute__((address_space(3))) void*)l, 16, 0, 0);
}

// ---------------- f32 -> bf16 convert ----------------
__global__ __launch_bounds__(256) void cvt_bf16(const float* __restrict__ in,
                                                u16* __restrict__ out, int n4) {
  for (long i = (long)blockIdx.x * 256 + threadIdx.x; i < n4; i += (long)gridDim.x * 256) {
    const float4 v = ((const float4*)in)[i];
    ushort4 o;
    o.x = f2b(v.x); o.y = f2b(v.y); o.z = f2b(v.z); o.w = f2b(v.w);
    ((ushort4*)out)[i] = o;
  }
}

// ---------------- GEMM: C(MxN) = A(MxK) * B(NxK)^T, bf16 in, OutT out -------
// 256x128 tile, BK=32, 8 waves (4M x 2N, per-wave 64x64), ring-4 LDS (96 KiB),
// counted vmcnt(6) pipeline (T4), chunk-XOR swizzle (T2), setprio (T5),
// XCD-chunked column-major block mapping (T1). Requires M%256==0, N%128==0,
// K%32==0, K/32>=3, grid=(M/256)*(N/128) with grid%8==0.
__device__ __forceinline__ short8 frag_ld(const u16* base, int rbase, int fr, int fq) {
  const int r = rbase + fr;
  return *(const short8*)(base + r * 32 + ((fq ^ ((r >> 1) & 3)) << 3));
}

template <typename OutT>
__global__ __launch_bounds__(512, 2) void gemm256(const u16* __restrict__ A,
                                                  const u16* __restrict__ B,
                                                  OutT* __restrict__ C,
                                                  int M, int N, int K) {
  __shared__ u16 lds[4 * 12288];          // 4 slots x (A 8192 + B 4096) u16
  const int tid = threadIdx.x;
  const int wid = tid >> 6, lane = tid & 63;
  const int fr = lane & 15, fq = lane >> 4;
  const int mA = (wid >> 1) * 64;         // wave row base within tile
  const int nB = (wid & 1) * 64;          // wave col base within tile

  // XCD-chunked column-major tile mapping (grid % 8 == 0)
  const int nty = M >> 8;                 // tiles along M (256)
  const int q = gridDim.x >> 3;
  const int wg = (blockIdx.x & 7) * q + (blockIdx.x >> 3);
  const int by = wg % nty;
  const int bx = wg / nty;
  const long row0 = (long)by * 256;
  const long col0 = (long)bx * 128;

  // staging: 3 x 16B chunks per thread per K-tile (A: 1024 chunks, B: 512)
  const int c0 = tid, c1 = 512 + tid, cB = tid;
  const int rA0 = c0 >> 2, j0 = (c0 & 3) ^ ((rA0 >> 1) & 3);
  const int rA1 = c1 >> 2, j1 = (c1 & 3) ^ ((rA1 >> 1) & 3);
  const int rB  = cB >> 2, j2 = (cB & 3) ^ ((rB >> 1) & 3);
  const u16* gA0 = A + (row0 + rA0) * (long)K + j0 * 8;
  const u16* gA1 = A + (row0 + rA1) * (long)K + j1 * 8;
  const u16* gB  = B + (col0 + rB) * (long)K + j2 * 8;
  const int dA0 = c0 * 8, dA1 = c1 * 8, dB = 8192 + cB * 8;

  f32x4 acc[4][4];
#pragma unroll
  for (int m = 0; m < 4; ++m)
#pragma unroll
    for (int n = 0; n < 4; ++n) acc[m][n] = f32x4{0.f, 0.f, 0.f, 0.f};

  const int NT = K >> 5;

  // prologue: stage tiles 0,1,2 into slots 0,1,2; wait tile 0 (2 tiles in flight)
#pragma unroll
  for (int pt = 0; pt < 3; ++pt) {
    u16* s = lds + pt * 12288;
    gload_lds16(gA0 + pt * 32, s + dA0);
    gload_lds16(gA1 + pt * 32, s + dA1);
    gload_lds16(gB  + pt * 32, s + dB);
  }
  asm volatile("s_waitcnt vmcnt(6)" ::: "memory");
  __builtin_amdgcn_s_barrier();

  for (int t = 0; t < NT; ++t) {
    const u16* SA = lds + (t & 3) * 12288;
    const u16* SB = SA + 8192;
    u16* ST = lds + ((t + 3) & 3) * 12288;
    const bool st = (t + 3) < NT;
    const int sk = (t + 3) * 32;

    // ---- phase 1: frags m0,m1 + all B; stage 2 chunks; 8 MFMA ----
    short8 a0 = frag_ld(SA, mA +  0, fr, fq);
    short8 a1 = frag_ld(SA, mA + 16, fr, fq);
    short8 b0 = frag_ld(SB, nB +  0, fr, fq);
    short8 b1 = frag_ld(SB, nB + 16, fr, fq);
    short8 b2 = frag_ld(SB, nB + 32, fr, fq);
    short8 b3 = frag_ld(SB, nB + 48, fr, fq);
    if (st) {
      gload_lds16(gA0 + sk, ST + dA0);
      gload_lds16(gA1 + sk, ST + dA1);
    }
    __builtin_amdgcn_s_barrier();
    __builtin_amdgcn_s_setprio(1);
    acc[0][0] = __builtin_amdgcn_mfma_f32_16x16x32_bf16(a0, b0, acc[0][0], 0, 0, 0);
    acc[0][1] = __builtin_amdgcn_mfma_f32_16x16x32_bf16(a0, b1, acc[0][1], 0, 0, 0);
    acc[0][2] = __builtin_amdgcn_mfma_f32_16x16x32_bf16(a0, b2, acc[0][2], 0, 0, 0);
    acc[0][3] = __builtin_amdgcn_mfma_f32_16x16x32_bf16(a0, b3, acc[0][3], 0, 0, 0);
    acc[1][0] = __builtin_amdgcn_mfma_f32_16x16x32_bf16(a1, b0, acc[1][0], 0, 0, 0);
    acc[1][1] = __builtin_amdgcn_mfma_f32_16x16x32_bf16(a1, b1, acc[1][1], 0, 0, 0);
    acc[1][2] = __builtin_amdgcn_mfma_f32_16x16x32_bf16(a1, b2, acc[1][2], 0, 0, 0);
    acc[1][3] = __builtin_amdgcn_mfma_f32_16x16x32_bf16(a1, b3, acc[1][3], 0, 0, 0);
    __builtin_amdgcn_s_setprio(0);
    __builtin_amdgcn_s_barrier();

    // ---- phase 2: frags m2,m3 (reuse B); stage 1 chunk; 8 MFMA ----
    short8 a2 = frag_ld(SA, mA + 32, fr, fq);
    short8 a3 = frag_ld(SA, mA + 48, fr, fq);
    if (st) gload_lds16(gB + sk, ST + dB);
    __builtin_amdgcn_s_barrier();
    __builtin_amdgcn_s_setprio(1);
    acc[2][0] = __builtin_amdgcn_mfma_f32_16x16x32_bf16(a2, b0, acc[2][0], 0, 0, 0);
    acc[2][1] = __builtin_amdgcn_mfma_f32_16x16x32_bf16(a2, b1, acc[2][1], 0, 0, 0);
    acc[2][2] = __builtin_amdgcn_mfma_f32_16x16x32_bf16(a2, b2, acc[2][2], 0, 0, 0);
    acc[2][3] = __builtin_amdgcn_mfma_f32_16x16x32_bf16(a2, b3, acc[2][3], 0, 0, 0);
    acc[3][0] = __builtin_amdgcn_mfma_f32_16x16x32_bf16(a3, b0, acc[3][0], 0, 0, 0);
    acc[3][1] = __builtin_amdgcn_mfma_f32_16x16x32_bf16(a3, b1, acc[3][1], 0, 0, 0);
    acc[3][2] = __builtin_amdgcn_mfma_f32_16x16x32_bf16(a3, b2, acc[3][2], 0, 0, 0);
    acc[3][3] = __builtin_amdgcn_mfma_f32_16x16x32_bf16(a3, b3, acc[3][3], 0, 0, 0);
    __builtin_amdgcn_s_setprio(0);
    // counted wait: tile t+1 landed; tiles t+2 (3) / t+3 (3) may stay in flight
    if (t + 3 < NT)      asm volatile("s_waitcnt vmcnt(6)" ::: "memory");
    else if (t + 2 < NT) asm volatile("s_waitcnt vmcnt(3)" ::: "memory");
    else                 asm volatile("s_waitcnt vmcnt(0)" ::: "memory");
    __builtin_amdgcn_s_barrier();
  }

#pragma unroll
  for (int m = 0; m < 4; ++m)
#pragma unroll
    for (int n = 0; n < 4; ++n)
#pragma unroll
      for (int j = 0; j < 4; ++j) {
        const long r = row0 + mA + m * 16 + fq * 4 + j;
        const long c = col0 + nB + n * 16 + fr;
        if constexpr (sizeof(OutT) == 2) C[r * N + c] = f2b(acc[m][n][j]);
        else                             C[r * N + c] = acc[m][n][j];
      }
}

// ---------------- RoPE in-place on q,k (cols 0..8191 of qkv) ----------------
__global__ __launch_bounds__(256) void rope_qk(u16* __restrict__ qkv,
                                               const float* __restrict__ cosb,
                                               const float* __restrict__ sinb) {
  const int s = blockIdx.x;
  __shared__ u16 row[8192];
  const uint4* src = (const uint4*)(qkv + (long)s * 12288);
  uint4* dst = (uint4*)row;
  for (int i = threadIdx.x; i < 1024; i += 256) dst[i] = src[i];
  __syncthreads();
  const float scale = 0.08838834764831845f;  // 1/sqrt(128)
  for (int i = threadIdx.x; i < 8192; i += 256) {
    const int d = i & 127;
    const int base = i & ~127;
    const float x  = b2f(row[i]);
    const float x2 = b2f(row[base + ((d + 64) & 127)]);
    const float c  = cosb[s * 128 + d];
    const float sn = sinb[s * 128 + d];
    float v = x * c + ((d < 64) ? -x2 : x2) * sn;
    if (i < 4096) v *= scale;                // q only
    qkv[(long)s * 12288 + i] = f2b(v);
  }
}

// ---------------- transpose V: qkv[:,8192+f] (S x 4096) -> vt (4096 x S) ----
__global__ __launch_bounds__(256) void transpose_v(const u16* __restrict__ qkv,
                                                   u16* __restrict__ vt) {
  __shared__ u16 tile[64][72];
  const int f0 = blockIdx.x * 64;
  const int s0 = blockIdx.y * 64;
  const int tid = threadIdx.x;
  const int rr = tid >> 3;
  const int cc = (tid & 7) * 8;
#pragma unroll
  for (int p = 0; p < 2; ++p) {
    const int sr = p * 32 + rr;
    *(uint4*)&tile[sr][cc] =
        *(const uint4*)(qkv + (long)(s0 + sr) * 12288 + 8192 + f0 + cc);
  }
  __syncthreads();
#pragma unroll
  for (int p = 0; p < 2; ++p) {
    const int fr = p * 32 + rr;
    u16 tmp[8];
#pragma unroll
    for (int j = 0; j < 8; ++j) tmp[j] = tile[cc + j][fr];
    *(uint4*)(vt + (long)(f0 + fr) * 2048 + s0 + cc) = *(uint4*)tmp;
  }
}

// ---------------- causal flash attention ------------------------------------
__global__ __launch_bounds__(256) void attn_fwd(const u16* __restrict__ Qb,
                                                const u16* __restrict__ Kb,
                                                const u16* __restrict__ Vt,
                                                u16* __restrict__ Ob) {
  const int h  = blockIdx.y;
  const int q0 = blockIdx.x * 64;
  const int tid = threadIdx.x;
  const int wid = tid >> 6, lane = tid & 63;
  const int fr = lane & 15, fq = lane >> 4;

  __shared__ u16 Ks[64 * 128];
  __shared__ u16 Vts[128 * 64];
  __shared__ u16 Ps[4][16 * 72];

  short8 qf[4];
  {
    const long qrow = q0 + wid * 16 + fr;
#pragma unroll
    for (int kk = 0; kk < 4; ++kk)
      qf[kk] = *(const short8*)(Qb + qrow * 12288 + h * 128 + kk * 32 + fq * 8);
  }

  f32x4 Oacc[8];
#pragma unroll
  for (int f = 0; f < 8; ++f) Oacc[f] = f32x4{0.f, 0.f, 0.f, 0.f};
  float mrun[4], lrun[4];
#pragma unroll
  for (int j = 0; j < 4; ++j) { mrun[j] = -1e30f; lrun[j] = 0.f; }

  const int nt = blockIdx.x + 1;
  for (int t = 0; t < nt; ++t) {
    const int kv0 = t * 64;
#pragma unroll
    for (int i = 0; i < 4; ++i) {
      const int c = wid * 4 + i;
      {
        const int r = c * 4 + (lane >> 4);
        const int p = lane & 15;
        const int jsrc = p ^ (r & 7);
        gload_lds16(Kb + (long)(kv0 + r) * 12288 + h * 128 + jsrc * 8,
                    (char*)Ks + c * 1024);
      }
      {
        const int d = c * 8 + (lane >> 3);
        const int p = lane & 7;
        const int jsrc = p ^ (d & 7);
        gload_lds16(Vt + (long)(h * 128 + d) * 2048 + kv0 + jsrc * 8,
                    (char*)Vts + c * 1024);
      }
    }
    __syncthreads();

    f32x4 S[4];
#pragma unroll
    for (int n = 0; n < 4; ++n) S[n] = f32x4{0.f, 0.f, 0.f, 0.f};
#pragma unroll
    for (int kk = 0; kk < 4; ++kk) {
#pragma unroll
      for (int n = 0; n < 4; ++n) {
        const int r = n * 16 + fr;
        const int p = (kk * 4 + fq) ^ (r & 7);
        short8 kf = *(const short8*)((const char*)Ks + r * 256 + p * 16);
        S[n] = __builtin_amdgcn_mfma_f32_16x16x32_bf16(qf[kk], kf, S[n], 0, 0, 0);
      }
    }

    float P[4][4];
    float tm[4] = {-1e30f, -1e30f, -1e30f, -1e30f};
#pragma unroll
    for (int n = 0; n < 4; ++n) {
      const int kv = kv0 + n * 16 + fr;
#pragma unroll
      for (int j = 0; j < 4; ++j) {
        const int qi = q0 + wid * 16 + fq * 4 + j;
        const float s = (kv <= qi) ? S[n][j] : -1e30f;
        P[n][j] = s;
        tm[j] = fmaxf(tm[j], s);
      }
    }
#pragma unroll
    for (int j = 0; j < 4; ++j)
#pragma unroll
      for (int msk = 1; msk < 16; msk <<= 1)
        tm[j] = fmaxf(tm[j], __shfl_xor(tm[j], msk));

    float al[4], rs[4];
#pragma unroll
    for (int j = 0; j < 4; ++j) {
      const float mn = fmaxf(mrun[j], tm[j]);
      al[j] = __expf(mrun[j] - mn);
      mrun[j] = mn;
      rs[j] = 0.f;
    }
#pragma unroll
    for (int n = 0; n < 4; ++n)
#pragma unroll
      for (int j = 0; j < 4; ++j) {
        const float p = __expf(P[n][j] - mrun[j]);
        P[n][j] = p;
        rs[j] += p;
      }
#pragma unroll
    for (int j = 0; j < 4; ++j) {
#pragma unroll
      for (int msk = 1; msk < 16; msk <<= 1) rs[j] += __shfl_xor(rs[j], msk);
      lrun[j] = lrun[j] * al[j] + rs[j];
    }
#pragma unroll
    for (int f = 0; f < 8; ++f) {
      f32x4 o = Oacc[f];
#pragma unroll
      for (int j = 0; j < 4; ++j) o[j] *= al[j];
      Oacc[f] = o;
    }

#pragma unroll
    for (int n = 0; n < 4; ++n)
#pragma unroll
      for (int j = 0; j < 4; ++j)
        Ps[wid][(fq * 4 + j) * 72 + n * 16 + fr] = f2b(P[n][j]);

#pragma unroll
    for (int kb = 0; kb < 2; ++kb) {
      short8 pa = *(const short8*)(Ps[wid] + fr * 72 + kb * 32 + fq * 8);
#pragma unroll
      for (int f = 0; f < 8; ++f) {
        const int d = f * 16 + fr;
        const int p = (kb * 4 + fq) ^ (d & 7);
        short8 vf = *(const short8*)((const char*)Vts + d * 128 + p * 16);
        Oacc[f] = __builtin_amdgcn_mfma_f32_16x16x32_bf16(pa, vf, Oacc[f], 0, 0, 0);
      }
    }
    __syncthreads();
  }

#pragma unroll
  for (int j = 0; j < 4; ++j) {
    const float inv = 1.f / lrun[j];
    const long r = q0 + wid * 16 + fq * 4 + j;
#pragma unroll
    for (int f = 0; f < 8; ++f)
      Ob[r * 4096 + h * 128 + f * 16 + fr] = f2b(Oacc[f][j] * inv);
  }
}

// ---------------- launch ----------------------------------------------------
extern "C" void kernel_launch(void* const* d_in, const int* in_sizes, int n_in,
                              void* d_out, int out_size, void* d_ws, size_t ws_size,
                              hipStream_t stream) {
  const float* hs   = (const float*)d_in[0];   // (2048, 4096)
  const float* cosb = (const float*)d_in[1];   // (2048, 128)
  const float* sinb = (const float*)d_in[2];   // (2048, 128)
  const float* wp   = (const float*)d_in[3];   // (12288, 4096)
  const float* wo   = (const float*)d_in[4];   // (4096, 4096)
  float* out = (float*)d_out;                  // (2048, 4096)
  char* ws = (char*)d_ws;

  u16* wp_bf = (u16*)(ws);                       // 100,663,296 B
  u16* wo_bf = (u16*)(ws);                       //  33,554,432 B (after GEMM1)
  u16* h_bf  = (u16*)(ws + 100663296);           //  16,777,216 B
  u16* attn  = (u16*)(ws + 100663296);           //  16,777,216 B (after GEMM1)
  u16* qkv   = (u16*)(ws + 117440512);           //  50,331,648 B
  u16* vt    = (u16*)(ws + 167772160);           //  16,777,216 B

  cvt_bf16<<<2048, 256, 0, stream>>>(hs, h_bf, 8388608 / 4);
  cvt_bf16<<<4096, 256, 0, stream>>>(wp, wp_bf, 50331648 / 4);
  gemm256<u16><<<768, 512, 0, stream>>>(h_bf, wp_bf, qkv, 2048, 12288, 4096);
  rope_qk<<<2048, 256, 0, stream>>>(qkv, cosb, sinb);
  transpose_v<<<dim3(64, 32), 256, 0, stream>>>(qkv, vt);
  cvt_bf16<<<2048, 256, 0, stream>>>(wo, wo_bf, 16777216 / 4);
  attn_fwd<<<dim3(32, 32), 256, 0, stream>>>(qkv, qkv + 4096, vt, attn);
  gemm256<float><<<256, 512, 0, stream>>>(attn, wo_bf, out, 2048, 4096, 4096);
}